// Round 16
// baseline (41.108 us; speedup 1.0000x reference)
//
#include <hip/hip_runtime.h>
#include <cstddef>
#include <cstdint>

#define B_    8
#define T_EN_ 512
#define T_DE_ 128
#define D_    512
#define U_    256

// exp(2x) = 2^(C*x), C = 2*log2(e); tanh(a+e) = 1 - 2/(exp(2a)exp(2e)+1)
#define TANH_C 2.8853900817779268f
#define L2E_   1.4426950408889634f

typedef float f32x4 __attribute__((ext_vector_type(4)));
typedef float f32x2 __attribute__((ext_vector_type(2)));
typedef short s16x8 __attribute__((ext_vector_type(8)));

// proj epilogue: store exp(2*acc) (positive, d=EA*EB+1 >= 1 downstream)
__device__ __forceinline__ float exp2c(float x) {
  return __builtin_amdgcn_exp2f(x * TANH_C);
}

// split f32 -> bf16 hi (truncated) + bf16 lo (truncated remainder)
__device__ __forceinline__ void split_bf16(float x, short& hi, short& lo) {
  const unsigned u = __float_as_uint(x);
  hi = (short)(u >> 16);
  const float hf = __uint_as_float(u & 0xffff0000u);
  const float lf = x - hf;
  lo = (short)(__float_as_uint(lf) >> 16);
}

// ---------------------------------------------------------------------------
// Prepack (r5-r15-verified, verbatim): en/de/w_en/w_de -> bf16 hi/lo frag
// planes. k-map in 32-k step s: k = s*32 + g*4 + (e&3) + 16*(e>>2), lane=g*16+n.
// ---------------------------------------------------------------------------
__global__ __launch_bounds__(256) void prepack_kernel(
    const float* __restrict__ en, const float* __restrict__ de,
    const float* __restrict__ w_en, const float* __restrict__ w_de,
    short* __restrict__ en_hi, short* __restrict__ en_lo,
    short* __restrict__ de_hi, short* __restrict__ de_lo,
    short* __restrict__ wen_hi, short* __restrict__ wen_lo,
    short* __restrict__ wde_hi, short* __restrict__ wde_lo) {
  const int blk = blockIdx.x;
  const int tid = threadIdx.x;
  float v[8];
  short* ph;
  short* pl;
  size_t ub;

  if (blk < 1280) {
    const int gu = blk * 256 + tid;
    const int n = gu & 15;
    const int g = (gu >> 4) & 3;
    const int s = (gu >> 6) & 15;
    const int rb = gu >> 10;
    const float* src;
    if (rb < 256) {
      const int b = rb >> 5, t = rb & 31;
      src = en + ((size_t)rb * 16 + n) * D_;
      ub = ((size_t)((b * 16 + s) * 32 + t) * 4 + g) * 16 + n;
      ph = en_hi; pl = en_lo;
    } else {
      const int t64 = rb - 256;
      src = de + ((size_t)t64 * 16 + n) * D_;
      ub = ((size_t)(s * 64 + t64) * 4 + g) * 16 + n;
      ph = de_hi; pl = de_lo;
    }
    const int kb = s * 32 + g * 4;
    const float4 fa = *(const float4*)(src + kb);
    const float4 fb = *(const float4*)(src + kb + 16);
    v[0] = fa.x; v[1] = fa.y; v[2] = fa.z; v[3] = fa.w;
    v[4] = fb.x; v[5] = fb.y; v[6] = fb.z; v[7] = fb.w;
  } else {
    const int wb = blk - 1280;
    const bool is_en = wb < 64;
    const int wq = wb & 63;
    const int s = wq >> 2, USq = wq & 3;
    const int n = tid & 15;
    const int g = (tid >> 4) & 3;
    const int US = USq * 4 + (tid >> 6);
    const float* W = is_en ? w_en : w_de;
    ph = is_en ? wen_hi : wde_hi;
    pl = is_en ? wen_lo : wde_lo;
    #pragma unroll
    for (int e = 0; e < 8; ++e) {
      const int k = s * 32 + g * 4 + (e & 3) + 16 * (e >> 2);
      v[e] = W[(size_t)k * U_ + US * 16 + n];
    }
    ub = ((size_t)(s * 16 + US) * 4 + g) * 16 + n;
  }

  s16x8 h8, l8;
  #pragma unroll
  for (int e = 0; e < 8; ++e) {
    short h, l;
    split_bf16(v[e], h, l);
    h8[e] = h; l8[e] = l;
  }
  *(s16x8*)(ph + ub * 8) = h8;
  *(s16x8*)(pl + ub * 8) = l8;
}

// ---------------------------------------------------------------------------
// K1: MFMA projections + exp(2x) epilogue.
// r16 CHANGE: en i-tile 16 -> 32 (2 en-frag units per step, 12 MFMA/step) so
// each block's 256 KB w-frag read is amortized over 2x output: w-frag traffic
// 128 -> 64 MB. Grid 384: en blocks [0,256) (b=blk&7 XCD-pinned, uh, it of
// 32 i), de blocks [256,384) (verbatim r11 de branch).
// ---------------------------------------------------------------------------
__global__ __launch_bounds__(256) void mfma_proj_kernel(
    const short* __restrict__ en_hi, const short* __restrict__ en_lo,
    const short* __restrict__ de_hi, const short* __restrict__ de_lo,
    const short* __restrict__ wen_hi, const short* __restrict__ wen_lo,
    const short* __restrict__ wde_hi, const short* __restrict__ wde_lo,
    float* __restrict__ Et, float* __restrict__ de_t) {
  const int blk = blockIdx.x;
  const int tid = threadIdx.x;
  const int lane = tid & 63;
  const int wv = tid >> 6;
  const int rl = lane >> 4, cl = lane & 15;

  if (blk < 256) {
    const int b  = blk & 7;            // XCD-pinned
    const int uh = (blk >> 3) & 1;
    const int it = blk >> 4;           // 0..15, 32 i each
    const int US0 = uh * 8 + wv * 2;

    f32x4 acc[2][2] = {};              // [us][is]
    s16x8 bufA[8], bufB[8];            // 0..3 w (h0,l0,h1,l1), 4..7 en (h0,l0,h1,l1)

#define LOAD_EN(DST, S)                                                   \
    { const size_t oa0 = ((size_t)((S) * 16 + US0) * 64 + lane) * 8;      \
      const size_t ob0 = ((size_t)(((b * 16 + (S)) * 32 + it * 2)) * 64 + lane) * 8; \
      DST[0] = *(const s16x8*)(wen_hi + oa0);                             \
      DST[1] = *(const s16x8*)(wen_lo + oa0);                             \
      DST[2] = *(const s16x8*)(wen_hi + oa0 + 512);                       \
      DST[3] = *(const s16x8*)(wen_lo + oa0 + 512);                       \
      DST[4] = *(const s16x8*)(en_hi + ob0);                              \
      DST[5] = *(const s16x8*)(en_lo + ob0);                              \
      DST[6] = *(const s16x8*)(en_hi + ob0 + 512);                        \
      DST[7] = *(const s16x8*)(en_lo + ob0 + 512); }
#define MFMA_EN(S)                                                        \
    { acc[0][0] = __builtin_amdgcn_mfma_f32_16x16x32_bf16(S[0], S[4], acc[0][0], 0, 0, 0); \
      acc[0][0] = __builtin_amdgcn_mfma_f32_16x16x32_bf16(S[0], S[5], acc[0][0], 0, 0, 0); \
      acc[0][0] = __builtin_amdgcn_mfma_f32_16x16x32_bf16(S[1], S[4], acc[0][0], 0, 0, 0); \
      acc[0][1] = __builtin_amdgcn_mfma_f32_16x16x32_bf16(S[0], S[6], acc[0][1], 0, 0, 0); \
      acc[0][1] = __builtin_amdgcn_mfma_f32_16x16x32_bf16(S[0], S[7], acc[0][1], 0, 0, 0); \
      acc[0][1] = __builtin_amdgcn_mfma_f32_16x16x32_bf16(S[1], S[6], acc[0][1], 0, 0, 0); \
      acc[1][0] = __builtin_amdgcn_mfma_f32_16x16x32_bf16(S[2], S[4], acc[1][0], 0, 0, 0); \
      acc[1][0] = __builtin_amdgcn_mfma_f32_16x16x32_bf16(S[2], S[5], acc[1][0], 0, 0, 0); \
      acc[1][0] = __builtin_amdgcn_mfma_f32_16x16x32_bf16(S[3], S[4], acc[1][0], 0, 0, 0); \
      acc[1][1] = __builtin_amdgcn_mfma_f32_16x16x32_bf16(S[2], S[6], acc[1][1], 0, 0, 0); \
      acc[1][1] = __builtin_amdgcn_mfma_f32_16x16x32_bf16(S[2], S[7], acc[1][1], 0, 0, 0); \
      acc[1][1] = __builtin_amdgcn_mfma_f32_16x16x32_bf16(S[3], S[6], acc[1][1], 0, 0, 0); }

    LOAD_EN(bufA, 0)
    for (int s = 0; s < 16; s += 2) {
      LOAD_EN(bufB, s + 1)
      MFMA_EN(bufA)
      if (s + 2 < 16) LOAD_EN(bufA, s + 2)
      MFMA_EN(bufB)
    }
#undef LOAD_EN
#undef MFMA_EN

    #pragma unroll
    for (int us = 0; us < 2; ++us) {
      #pragma unroll
      for (int is = 0; is < 2; ++is) {
        #pragma unroll
        for (int r = 0; r < 4; ++r) {
          const int u = (US0 + us) * 16 + rl * 4 + r;
          const int i = it * 32 + is * 16 + cl;
          Et[((size_t)b * U_ + u) * T_EN_ + i] = exp2c(acc[us][is][r]);
        }
      }
    }
  } else {
    const int y = blk - 256;
    const int t64 = y >> 1;
    const int uh = y & 1;
    const int US0 = uh * 8 + wv * 2;

    f32x4 acc[2] = {};
    s16x8 bufA[6], bufB[6];

#define LOAD_DE(DST, S)                                                   \
    { const size_t oa = ((size_t)((S) * 64 + t64) * 64 + lane) * 8;       \
      const size_t ob = ((size_t)((S) * 16 + US0) * 64 + lane) * 8;       \
      DST[0] = *(const s16x8*)(de_hi + oa);                               \
      DST[1] = *(const s16x8*)(de_lo + oa);                               \
      DST[2] = *(const s16x8*)(wde_hi + ob);                              \
      DST[3] = *(const s16x8*)(wde_lo + ob);                              \
      DST[4] = *(const s16x8*)(wde_hi + ob + 512);                        \
      DST[5] = *(const s16x8*)(wde_lo + ob + 512); }
#define MFMA_DE(S)                                                        \
    { acc[0] = __builtin_amdgcn_mfma_f32_16x16x32_bf16(S[0], S[2], acc[0], 0, 0, 0); \
      acc[0] = __builtin_amdgcn_mfma_f32_16x16x32_bf16(S[0], S[3], acc[0], 0, 0, 0); \
      acc[0] = __builtin_amdgcn_mfma_f32_16x16x32_bf16(S[1], S[2], acc[0], 0, 0, 0); \
      acc[1] = __builtin_amdgcn_mfma_f32_16x16x32_bf16(S[0], S[4], acc[1], 0, 0, 0); \
      acc[1] = __builtin_amdgcn_mfma_f32_16x16x32_bf16(S[0], S[5], acc[1], 0, 0, 0); \
      acc[1] = __builtin_amdgcn_mfma_f32_16x16x32_bf16(S[1], S[4], acc[1], 0, 0, 0); }

    LOAD_DE(bufA, 0)
    for (int s = 0; s < 16; s += 2) {
      LOAD_DE(bufB, s + 1)
      MFMA_DE(bufA)
      if (s + 2 < 16) LOAD_DE(bufA, s + 2)
      MFMA_DE(bufB)
    }
#undef LOAD_DE
#undef MFMA_DE

    #pragma unroll
    for (int us = 0; us < 2; ++us) {
      #pragma unroll
      for (int r = 0; r < 4; ++r) {
        const int j = t64 * 16 + rl * 4 + r;
        const int u = (US0 + us) * 16 + cl;
        de_t[(size_t)j * U_ + u] = exp2c(acc[us][r]);
      }
    }
  }
}

// ---------------------------------------------------------------------------
// K2 v10: mu' only (softmax split out). mu' = -2*sum_u nu_u/(EA*EB+1).
// r16 CHANGE: 8 j per block (E re-read once per 8 j -> 64 MB total, halved).
// grid 256 = (jo*2 + ih)*8 + b: b = blk&7 (XCD-pinned), ih = (blk>>3)&1
// (i-half), jo = blk>>4 (j-octet). Wave = u-octant (16 pairs) x 256 i
// (4 i/lane). Partials mu_p[8][8][256] in LDS; wave w combines j-local w
// and writes raw mu' to the mu buffer (mask/softmax in K3).
// ---------------------------------------------------------------------------
__global__ __launch_bounds__(512) void attn_mu_kernel(
    const float* __restrict__ Et, const float* __restrict__ de_t,
    const float* __restrict__ nu, float* __restrict__ mu) {
  __shared__ f32x2 Ea_s[8][U_ / 2];     // {EA1,EA2} per (j-local, u-pair) 8 KB
  __shared__ f32x2 nv2_s[U_ / 2];       // {nu1,nu2} per pair, 1 KB
  __shared__ float mu_p[8][8][256];     // [u-oct][j-local][i-local] 64 KB

  const int tid  = threadIdx.x;
  const int lane = tid & 63;
  const int w    = tid >> 6;           // u-octant 0..7
  const int b    = blockIdx.x & 7;
  const int ih   = (blockIdx.x >> 3) & 1;
  const int jo   = blockIdx.x >> 4;    // 0..15
  const int j0   = jo * 8;

  // ---- prologue: per-(j, u-pair) constants (1024 entries, 2 per thread) ----
  #pragma unroll
  for (int e0 = 0; e0 < 2; ++e0) {
    const int e = tid + e0 * 512;
    const int jl = e >> 7;             // 0..7
    const int p  = e & 127;
    const float2 Av = *(const float2*)(de_t + (size_t)(b * T_DE_ + j0 + jl) * U_ + 2 * p);
    f32x2 L; L[0] = Av.x; L[1] = Av.y;
    Ea_s[jl][p] = L;
  }
  if (tid < 128) {
    const float2 n2 = *(const float2*)(nu + 2 * tid);
    f32x2 v; v[0] = n2.x; v[1] = n2.y;
    nv2_s[tid] = v;
  }
  __syncthreads();

  const int pb = w * 16;               // this wave's 16 pairs (32 u)
  const float* __restrict__ Eb =
      Et + ((size_t)b * U_ + 2 * pb) * T_EN_ + ih * 256 + lane * 4;

  const f32x4 one4 = {1.f, 1.f, 1.f, 1.f};
  f32x4 acc[8] = {};                   // per j-local

  f32x4 E1a, E2a, E1b, E2b;
  f32x2 La[8], Lb[8];
  f32x2 nva, nvb;

#define LOADP(SUF, P)                                                     \
  { const float* e1 = Eb + (size_t)(2 * (P)) * T_EN_;                     \
    E1##SUF = *(const f32x4*)(e1);                                        \
    E2##SUF = *(const f32x4*)(e1 + T_EN_);                                \
    _Pragma("unroll")                                                     \
    for (int jl = 0; jl < 8; ++jl) L##SUF[jl] = Ea_s[jl][pb + (P)];       \
    nv##SUF = nv2_s[pb + (P)]; }

#define COMPP(SUF)                                                        \
  { _Pragma("unroll")                                                     \
    for (int jl = 0; jl < 8; ++jl) {                                      \
      const f32x2 Lc = L##SUF[jl];                                        \
      const f32x4 d1 = E1##SUF * Lc[0] + one4;                            \
      const f32x4 d2 = E2##SUF * Lc[1] + one4;                            \
      const f32x4 t  = d2 * nv##SUF[0];                                   \
      const f32x4 num = d1 * nv##SUF[1] + t;                              \
      const f32x4 Dd = d1 * d2;                                           \
      f32x4 r;                                                            \
      r[0] = __builtin_amdgcn_rcpf(Dd[0]);                                \
      r[1] = __builtin_amdgcn_rcpf(Dd[1]);                                \
      r[2] = __builtin_amdgcn_rcpf(Dd[2]);                                \
      r[3] = __builtin_amdgcn_rcpf(Dd[3]);                                \
      acc[jl] = num * r + acc[jl];                                        \
    } }

  LOADP(a, 0)
  for (int p0 = 0; p0 < 16; p0 += 2) {
    LOADP(b, p0 + 1)
    COMPP(a)
    if (p0 + 2 < 16) LOADP(a, p0 + 2)
    COMPP(b)
  }
#undef LOADP
#undef COMPP

  #pragma unroll
  for (int jl = 0; jl < 8; ++jl)
    *(f32x4*)&mu_p[w][jl][lane * 4] = acc[jl];
  __syncthreads();

  // ---- combine 8 u-octant partials; wave w owns j-local w ----
  {
    f32x4 s = {0.f, 0.f, 0.f, 0.f};
    #pragma unroll
    for (int uo = 0; uo < 8; ++uo)
      s += *(const f32x4*)&mu_p[uo][w][lane * 4];
    const f32x4 o = s * -2.0f;
    *(f32x4*)(mu + (size_t)(b * T_DE_ + j0 + w) * T_EN_ + ih * 256 + lane * 4) = o;
  }
}

// ---------------------------------------------------------------------------
// K3: masked softmax over mu rows (r14-verified softmax body).
// grid 128 x 512: wave handles one flat j-row (1024 rows of 512).
// ---------------------------------------------------------------------------
__global__ __launch_bounds__(512) void softmax_kernel(
    const float* __restrict__ mu, const int* __restrict__ mask,
    float* __restrict__ out) {
  const int tid  = threadIdx.x;
  const int lane = tid & 63;
  const int jd   = blockIdx.x * 8 + (tid >> 6);  // 0..1023
  const int b    = jd >> 7;

  const float* mp = mu + (size_t)jd * T_EN_;
  float vals[8];
  float mx = -3.0e38f;
  #pragma unroll
  for (int k = 0; k < 8; ++k) {
    const int i = lane + 64 * k;
    const float mi = (float)mask[b * T_EN_ + i];
    const float v = fmaf(mi - 1.0f, 1.0e6f, mp[i]);
    vals[k] = v;
    mx = fmaxf(mx, v);
  }
  #pragma unroll
  for (int off = 32; off; off >>= 1) mx = fmaxf(mx, __shfl_xor(mx, off, 64));
  float sum = 0.0f;
  #pragma unroll
  for (int k = 0; k < 8; ++k) {
    const float e = __builtin_amdgcn_exp2f((vals[k] - mx) * L2E_);
    vals[k] = e;
    sum += e;
  }
  #pragma unroll
  for (int off = 32; off; off >>= 1) sum += __shfl_xor(sum, off, 64);
  const float inv = __builtin_amdgcn_rcpf(sum);
  float* op = out + (size_t)jd * T_EN_;
  #pragma unroll
  for (int k = 0; k < 8; ++k) op[lane + 64 * k] = vals[k] * inv;
}

// ---------------------------------------------------------------------------
extern "C" void kernel_launch(void* const* d_in, const int* in_sizes, int n_in,
                              void* d_out, int out_size, void* d_ws, size_t ws_size,
                              hipStream_t stream) {
  const float* en   = (const float*)d_in[0];   // [B, T_EN, D]
  const float* de   = (const float*)d_in[1];   // [B, T_DE, D]
  const int*   mask = (const int*)d_in[2];     // [B, T_EN]
  const float* w_en = (const float*)d_in[3];   // [D, U]
  const float* w_de = (const float*)d_in[4];   // [D, U]
  const float* nu   = (const float*)d_in[5];   // [U, 1]
  float* out = (float*)d_out;                  // [B, T_DE, T_EN]

  // ws layout (18 MB; ws verified >= 16 MB since r5 -- harness ws is 256 MB
  // per WRITE_SIZE of its poison fills)
  float* Et   = (float*)d_ws;                  // exp(2*en@w_en)^T [B][U][T_EN]  4 MB
  float* de_t = Et + (size_t)B_ * U_ * T_EN_;  // exp(2*de@w_de)   [B*T_DE][U]   1 MB
  float* muB  = de_t + (size_t)B_ * T_DE_ * U_;        // logits [1024][512]      2 MB
  short* p    = (short*)(muB + (size_t)B_ * T_DE_ * T_EN_);
  short* en_hi = p;                 p += 2097152;   // B*T_EN*D
  short* en_lo = p;                 p += 2097152;
  short* de_hi = p;                 p += 524288;    // B*T_DE*D
  short* de_lo = p;                 p += 524288;
  short* wen_hi = p;                p += 131072;    // D*U
  short* wen_lo = p;                p += 131072;
  short* wde_hi = p;                p += 131072;
  short* wde_lo = p;                p += 131072;

  prepack_kernel<<<dim3(1408), 256, 0, stream>>>(
      en, de, w_en, w_de, en_hi, en_lo, de_hi, de_lo,
      wen_hi, wen_lo, wde_hi, wde_lo);
  mfma_proj_kernel<<<dim3(384), 256, 0, stream>>>(
      en_hi, en_lo, de_hi, de_lo, wen_hi, wen_lo, wde_hi, wde_lo, Et, de_t);
  attn_mu_kernel<<<dim3(256), 512, 0, stream>>>(Et, de_t, nu, muB);
  softmax_kernel<<<dim3(128), 512, 0, stream>>>(muB, mask, out);
}

// Round 17
// 37.728 us; speedup vs baseline: 1.0896x; 1.0896x over previous
//
#include <hip/hip_runtime.h>
#include <cstddef>
#include <cstdint>

#define B_    8
#define T_EN_ 512
#define T_DE_ 128
#define D_    512
#define U_    256

// exp(2x) = 2^(C*x), C = 2*log2(e); tanh(a+e) = 1 - 2/(exp(2a)exp(2e)+1)
#define TANH_C 2.8853900817779268f
#define L2E_   1.4426950408889634f

typedef float f32x4 __attribute__((ext_vector_type(4)));
typedef float f32x2 __attribute__((ext_vector_type(2)));
typedef short s16x8 __attribute__((ext_vector_type(8)));

// proj epilogue: store exp(2*acc) (positive, d=EA*EB+1 >= 1 downstream)
__device__ __forceinline__ float exp2c(float x) {
  return __builtin_amdgcn_exp2f(x * TANH_C);
}

// split f32 -> bf16 hi (truncated) + bf16 lo (truncated remainder)
__device__ __forceinline__ void split_bf16(float x, short& hi, short& lo) {
  const unsigned u = __float_as_uint(x);
  hi = (short)(u >> 16);
  const float hf = __uint_as_float(u & 0xffff0000u);
  const float lf = x - hf;
  lo = (short)(__float_as_uint(lf) >> 16);
}

// ---------------------------------------------------------------------------
// Prepack (r5-r16-verified, verbatim).
// k-map in 32-k step s: k = s*32 + g*4 + (e&3) + 16*(e>>2), lane = g*16+n.
// ---------------------------------------------------------------------------
__global__ __launch_bounds__(256) void prepack_kernel(
    const float* __restrict__ en, const float* __restrict__ de,
    const float* __restrict__ w_en, const float* __restrict__ w_de,
    short* __restrict__ en_hi, short* __restrict__ en_lo,
    short* __restrict__ de_hi, short* __restrict__ de_lo,
    short* __restrict__ wen_hi, short* __restrict__ wen_lo,
    short* __restrict__ wde_hi, short* __restrict__ wde_lo) {
  const int blk = blockIdx.x;
  const int tid = threadIdx.x;
  float v[8];
  short* ph;
  short* pl;
  size_t ub;

  if (blk < 1280) {
    const int gu = blk * 256 + tid;
    const int n = gu & 15;
    const int g = (gu >> 4) & 3;
    const int s = (gu >> 6) & 15;
    const int rb = gu >> 10;
    const float* src;
    if (rb < 256) {
      const int b = rb >> 5, t = rb & 31;
      src = en + ((size_t)rb * 16 + n) * D_;
      ub = ((size_t)((b * 16 + s) * 32 + t) * 4 + g) * 16 + n;
      ph = en_hi; pl = en_lo;
    } else {
      const int t64 = rb - 256;
      src = de + ((size_t)t64 * 16 + n) * D_;
      ub = ((size_t)(s * 64 + t64) * 4 + g) * 16 + n;
      ph = de_hi; pl = de_lo;
    }
    const int kb = s * 32 + g * 4;
    const float4 fa = *(const float4*)(src + kb);
    const float4 fb = *(const float4*)(src + kb + 16);
    v[0] = fa.x; v[1] = fa.y; v[2] = fa.z; v[3] = fa.w;
    v[4] = fb.x; v[5] = fb.y; v[6] = fb.z; v[7] = fb.w;
  } else {
    const int wb = blk - 1280;
    const bool is_en = wb < 64;
    const int wq = wb & 63;
    const int s = wq >> 2, USq = wq & 3;
    const int n = tid & 15;
    const int g = (tid >> 4) & 3;
    const int US = USq * 4 + (tid >> 6);
    const float* W = is_en ? w_en : w_de;
    ph = is_en ? wen_hi : wde_hi;
    pl = is_en ? wen_lo : wde_lo;
    #pragma unroll
    for (int e = 0; e < 8; ++e) {
      const int k = s * 32 + g * 4 + (e & 3) + 16 * (e >> 2);
      v[e] = W[(size_t)k * U_ + US * 16 + n];
    }
    ub = ((size_t)(s * 16 + US) * 4 + g) * 16 + n;
  }

  s16x8 h8, l8;
  #pragma unroll
  for (int e = 0; e < 8; ++e) {
    short h, l;
    split_bf16(v[e], h, l);
    h8[e] = h; l8[e] = l;
  }
  *(s16x8*)(ph + ub * 8) = h8;
  *(s16x8*)(pl + ub * 8) = l8;
}

// ---------------------------------------------------------------------------
// K1: MFMA projections + exp(2x) epilogue (r15 bodies).
// r17 CHANGE: 4-stage software pipeline (prefetch depth 2 -> 4). In-flight
// load distance ~3 MFMA-groups (~225+ cyc at 2.5 waves/SIMD) covers the
// ~200 cyc L2 latency that made the 2-stage version latency-bound.
// ---------------------------------------------------------------------------
__global__ __launch_bounds__(256) void mfma_proj_kernel(
    const short* __restrict__ en_hi, const short* __restrict__ en_lo,
    const short* __restrict__ de_hi, const short* __restrict__ de_lo,
    const short* __restrict__ wen_hi, const short* __restrict__ wen_lo,
    const short* __restrict__ wde_hi, const short* __restrict__ wde_lo,
    float* __restrict__ Et, float* __restrict__ de_t) {
  const int blk = blockIdx.x;
  const int tid = threadIdx.x;
  const int lane = tid & 63;
  const int wv = tid >> 6;
  const int rl = lane >> 4, cl = lane & 15;

  f32x4 acc[2] = {};
  s16x8 bA[6], bB[6], bC[6], bD[6];

  if (blk < 512) {
    const int b  = blk & 7;            // XCD-pinned
    const int uh = (blk >> 3) & 1;
    const int it = blk >> 4;           // 0..31
    const int US0 = uh * 8 + wv * 2;

#define LOAD_EN(DST, S)                                                   \
    { const size_t oa0 = ((size_t)((S) * 16 + US0) * 64 + lane) * 8;      \
      const size_t ob  = ((size_t)((b * 16 + (S)) * 32 + it) * 64 + lane) * 8; \
      DST[0] = *(const s16x8*)(wen_hi + oa0);                             \
      DST[1] = *(const s16x8*)(wen_lo + oa0);                             \
      DST[2] = *(const s16x8*)(wen_hi + oa0 + 512);                       \
      DST[3] = *(const s16x8*)(wen_lo + oa0 + 512);                       \
      DST[4] = *(const s16x8*)(en_hi + ob);                               \
      DST[5] = *(const s16x8*)(en_lo + ob); }
#define MFMA_EN(S)                                                        \
    { acc[0] = __builtin_amdgcn_mfma_f32_16x16x32_bf16(S[0], S[4], acc[0], 0, 0, 0); \
      acc[0] = __builtin_amdgcn_mfma_f32_16x16x32_bf16(S[0], S[5], acc[0], 0, 0, 0); \
      acc[0] = __builtin_amdgcn_mfma_f32_16x16x32_bf16(S[1], S[4], acc[0], 0, 0, 0); \
      acc[1] = __builtin_amdgcn_mfma_f32_16x16x32_bf16(S[2], S[4], acc[1], 0, 0, 0); \
      acc[1] = __builtin_amdgcn_mfma_f32_16x16x32_bf16(S[2], S[5], acc[1], 0, 0, 0); \
      acc[1] = __builtin_amdgcn_mfma_f32_16x16x32_bf16(S[3], S[4], acc[1], 0, 0, 0); }

    LOAD_EN(bA, 0)
    LOAD_EN(bB, 1)
    LOAD_EN(bC, 2)
    LOAD_EN(bD, 3)
    #pragma unroll
    for (int s = 0; s < 16; s += 4) {
      MFMA_EN(bA)
      if (s + 4 < 16) LOAD_EN(bA, s + 4)
      MFMA_EN(bB)
      if (s + 5 < 16) LOAD_EN(bB, s + 5)
      MFMA_EN(bC)
      if (s + 6 < 16) LOAD_EN(bC, s + 6)
      MFMA_EN(bD)
      if (s + 7 < 16) LOAD_EN(bD, s + 7)
    }
#undef LOAD_EN
#undef MFMA_EN

    #pragma unroll
    for (int us = 0; us < 2; ++us) {
      #pragma unroll
      for (int r = 0; r < 4; ++r) {
        const int u = (US0 + us) * 16 + rl * 4 + r;
        const int i = it * 16 + cl;
        Et[((size_t)b * U_ + u) * T_EN_ + i] = exp2c(acc[us][r]);
      }
    }
  } else {
    const int y = blk - 512;
    const int t64 = y >> 1;
    const int uh = y & 1;
    const int US0 = uh * 8 + wv * 2;

#define LOAD_DE(DST, S)                                                   \
    { const size_t oa = ((size_t)((S) * 64 + t64) * 64 + lane) * 8;       \
      const size_t ob = ((size_t)((S) * 16 + US0) * 64 + lane) * 8;       \
      DST[0] = *(const s16x8*)(de_hi + oa);                               \
      DST[1] = *(const s16x8*)(de_lo + oa);                               \
      DST[2] = *(const s16x8*)(wde_hi + ob);                              \
      DST[3] = *(const s16x8*)(wde_lo + ob);                              \
      DST[4] = *(const s16x8*)(wde_hi + ob + 512);                        \
      DST[5] = *(const s16x8*)(wde_lo + ob + 512); }
#define MFMA_DE(S)                                                        \
    { acc[0] = __builtin_amdgcn_mfma_f32_16x16x32_bf16(S[0], S[2], acc[0], 0, 0, 0); \
      acc[0] = __builtin_amdgcn_mfma_f32_16x16x32_bf16(S[0], S[3], acc[0], 0, 0, 0); \
      acc[0] = __builtin_amdgcn_mfma_f32_16x16x32_bf16(S[1], S[2], acc[0], 0, 0, 0); \
      acc[1] = __builtin_amdgcn_mfma_f32_16x16x32_bf16(S[0], S[4], acc[1], 0, 0, 0); \
      acc[1] = __builtin_amdgcn_mfma_f32_16x16x32_bf16(S[0], S[5], acc[1], 0, 0, 0); \
      acc[1] = __builtin_amdgcn_mfma_f32_16x16x32_bf16(S[1], S[4], acc[1], 0, 0, 0); }

    LOAD_DE(bA, 0)
    LOAD_DE(bB, 1)
    LOAD_DE(bC, 2)
    LOAD_DE(bD, 3)
    #pragma unroll
    for (int s = 0; s < 16; s += 4) {
      MFMA_DE(bA)
      if (s + 4 < 16) LOAD_DE(bA, s + 4)
      MFMA_DE(bB)
      if (s + 5 < 16) LOAD_DE(bB, s + 5)
      MFMA_DE(bC)
      if (s + 6 < 16) LOAD_DE(bC, s + 6)
      MFMA_DE(bD)
      if (s + 7 < 16) LOAD_DE(bD, s + 7)
    }
#undef LOAD_DE
#undef MFMA_DE

    #pragma unroll
    for (int us = 0; us < 2; ++us) {
      #pragma unroll
      for (int r = 0; r < 4; ++r) {
        const int j = t64 * 16 + rl * 4 + r;
        const int u = (US0 + us) * 16 + cl;
        de_t[(size_t)j * U_ + u] = exp2c(acc[us][r]);
      }
    }
  }
}

// ---------------------------------------------------------------------------
// K2 v9 (r15 math, verbatim): mu' = -2 * sum_u nu_u / (EA[j,u]*EB[u,i]+1).
// r17 CHANGE: 4-stage rolling prefetch over u-pairs (depth 2 -> 4). In-flight
// E-load distance ~3 COMPP (~500+ cyc) covers L2/L3 latency. All stage
// variables are named (statically indexed) -- no scratch risk.
// grid 256 = jg*8 + b, 512 thr = 8 u-octant waves; waves 0..3 do softmax.
// ---------------------------------------------------------------------------
__global__ __launch_bounds__(512) void attn_mu_softmax_kernel(
    const float* __restrict__ Et, const float* __restrict__ de_t,
    const float* __restrict__ nu, const int* __restrict__ mask,
    float* __restrict__ out) {
  __shared__ f32x2 Ea_s[4][U_ / 2];     // {EA1,EA2} per (j-local, u-pair) 4 KB
  __shared__ f32x2 nv2_s[U_ / 2];       // {nu1,nu2} per pair, 1 KB
  __shared__ float mu_p[8][4][T_EN_];   // partial sums, 64 KB

  const int tid  = threadIdx.x;
  const int lane = tid & 63;
  const int w    = tid >> 6;           // u-octant 0..7
  const int b    = blockIdx.x & 7;
  const int jg   = blockIdx.x >> 3;    // 0..31
  const int j0   = jg * 4;

  // ---- prologue: per-(j, u-pair) constants ----
  {
    const int jl = tid >> 7;           // 0..3
    const int p  = tid & 127;
    const float2 Av = *(const float2*)(de_t + (size_t)(b * T_DE_ + j0 + jl) * U_ + 2 * p);
    f32x2 L; L[0] = Av.x; L[1] = Av.y;
    Ea_s[jl][p] = L;
    if (tid < 128) {
      const float2 n2 = *(const float2*)(nu + 2 * tid);
      f32x2 v; v[0] = n2.x; v[1] = n2.y;
      nv2_s[tid] = v;
    }
  }
  __syncthreads();

  const int pb = w * 16;               // this wave's 16 pairs (32 u)
  const float* __restrict__ EbA =
      Et + ((size_t)b * U_ + 2 * pb) * T_EN_ + lane * 4;

  const f32x4 one4 = {1.f, 1.f, 1.f, 1.f};
  f32x4 accA[4] = {}, accB[4] = {};    // [j-local] x {i-quad A, B}

  // 4 pipeline stages, all named / statically indexed
  f32x4 E1A0, E1B0, E2A0, E2B0, E1A1, E1B1, E2A1, E2B1;
  f32x4 E1A2, E1B2, E2A2, E2B2, E1A3, E1B3, E2A3, E2B3;
  f32x2 L0[4], L1[4], L2[4], L3[4];
  f32x2 nv0, nv1, nv2, nv3;

#define LOADP(S, P)                                                       \
  { const float* e1 = EbA + (size_t)(2 * (P)) * T_EN_;                    \
    const float* e2 = e1 + T_EN_;                                         \
    E1A##S = *(const f32x4*)(e1);                                         \
    E1B##S = *(const f32x4*)(e1 + 256);                                   \
    E2A##S = *(const f32x4*)(e2);                                         \
    E2B##S = *(const f32x4*)(e2 + 256);                                   \
    L##S[0] = Ea_s[0][pb + (P)];                                          \
    L##S[1] = Ea_s[1][pb + (P)];                                          \
    L##S[2] = Ea_s[2][pb + (P)];                                          \
    L##S[3] = Ea_s[3][pb + (P)];                                          \
    nv##S = nv2_s[pb + (P)]; }

#define COMPP(S)                                                          \
  { _Pragma("unroll")                                                     \
    for (int jl = 0; jl < 4; ++jl) {                                      \
      const f32x2 Lc = L##S[jl];                                          \
      { const f32x4 d1 = E1A##S * Lc[0] + one4;                           \
        const f32x4 d2 = E2A##S * Lc[1] + one4;                           \
        const f32x4 t  = d2 * nv##S[0];                                   \
        const f32x4 num = d1 * nv##S[1] + t;                              \
        const f32x4 Dd = d1 * d2;                                         \
        f32x4 r;                                                          \
        r[0] = __builtin_amdgcn_rcpf(Dd[0]);                              \
        r[1] = __builtin_amdgcn_rcpf(Dd[1]);                              \
        r[2] = __builtin_amdgcn_rcpf(Dd[2]);                              \
        r[3] = __builtin_amdgcn_rcpf(Dd[3]);                              \
        accA[jl] = num * r + accA[jl]; }                                  \
      { const f32x4 d1 = E1B##S * Lc[0] + one4;                           \
        const f32x4 d2 = E2B##S * Lc[1] + one4;                           \
        const f32x4 t  = d2 * nv##S[0];                                   \
        const f32x4 num = d1 * nv##S[1] + t;                              \
        const f32x4 Dd = d1 * d2;                                         \
        f32x4 r;                                                          \
        r[0] = __builtin_amdgcn_rcpf(Dd[0]);                              \
        r[1] = __builtin_amdgcn_rcpf(Dd[1]);                              \
        r[2] = __builtin_amdgcn_rcpf(Dd[2]);                              \
        r[3] = __builtin_amdgcn_rcpf(Dd[3]);                              \
        accB[jl] = num * r + accB[jl]; }                                  \
    } }

  LOADP(0, 0)
  LOADP(1, 1)
  LOADP(2, 2)
  LOADP(3, 3)
  #pragma unroll
  for (int p0 = 0; p0 < 16; p0 += 4) {
    COMPP(0)
    if (p0 + 4 < 16) LOADP(0, p0 + 4)
    COMPP(1)
    if (p0 + 5 < 16) LOADP(1, p0 + 5)
    COMPP(2)
    if (p0 + 6 < 16) LOADP(2, p0 + 6)
    COMPP(3)
    if (p0 + 7 < 16) LOADP(3, p0 + 7)
  }
#undef LOADP
#undef COMPP

  #pragma unroll
  for (int jl = 0; jl < 4; ++jl) {
    *(f32x4*)&mu_p[w][jl][lane * 4] = accA[jl];
    *(f32x4*)&mu_p[w][jl][256 + lane * 4] = accB[jl];
  }
  __syncthreads();

  // ---- combine octant partials + masked softmax: waves 0..3, one j each ----
  if (w < 4) {
    float vals[8];
    float mx = -3.0e38f;
    #pragma unroll
    for (int h = 0; h < 2; ++h) {
      f32x4 s = {0.f, 0.f, 0.f, 0.f};
      #pragma unroll
      for (int uo = 0; uo < 8; ++uo)
        s += *(const f32x4*)&mu_p[uo][w][h * 256 + lane * 4];
      const int4 mk = *(const int4*)(mask + b * T_EN_ + h * 256 + lane * 4);
      const float v0 = fmaf((float)mk.x - 1.f, 1.0e6f, -2.f * s[0]);
      const float v1 = fmaf((float)mk.y - 1.f, 1.0e6f, -2.f * s[1]);
      const float v2 = fmaf((float)mk.z - 1.f, 1.0e6f, -2.f * s[2]);
      const float v3 = fmaf((float)mk.w - 1.f, 1.0e6f, -2.f * s[3]);
      vals[h * 4 + 0] = v0; vals[h * 4 + 1] = v1;
      vals[h * 4 + 2] = v2; vals[h * 4 + 3] = v3;
      mx = fmaxf(mx, fmaxf(fmaxf(v0, v1), fmaxf(v2, v3)));
    }
    #pragma unroll
    for (int off = 32; off; off >>= 1) mx = fmaxf(mx, __shfl_xor(mx, off, 64));
    float sum = 0.0f;
    #pragma unroll
    for (int k = 0; k < 8; ++k) {
      const float e = __builtin_amdgcn_exp2f((vals[k] - mx) * L2E_);
      vals[k] = e;
      sum += e;
    }
    #pragma unroll
    for (int off = 32; off; off >>= 1) sum += __shfl_xor(sum, off, 64);
    const float inv = __builtin_amdgcn_rcpf(sum);
    float* op = out + (size_t)(b * T_DE_ + j0 + w) * T_EN_;
    #pragma unroll
    for (int h = 0; h < 2; ++h) {
      const float4 o = make_float4(vals[h * 4 + 0] * inv, vals[h * 4 + 1] * inv,
                                   vals[h * 4 + 2] * inv, vals[h * 4 + 3] * inv);
      *(float4*)(op + h * 256 + lane * 4) = o;
    }
  }
}

// ---------------------------------------------------------------------------
extern "C" void kernel_launch(void* const* d_in, const int* in_sizes, int n_in,
                              void* d_out, int out_size, void* d_ws, size_t ws_size,
                              hipStream_t stream) {
  const float* en   = (const float*)d_in[0];   // [B, T_EN, D]
  const float* de   = (const float*)d_in[1];   // [B, T_DE, D]
  const int*   mask = (const int*)d_in[2];     // [B, T_EN]
  const float* w_en = (const float*)d_in[3];   // [D, U]
  const float* w_de = (const float*)d_in[4];   // [D, U]
  const float* nu   = (const float*)d_in[5];   // [U, 1]
  float* out = (float*)d_out;                  // [B, T_DE, T_EN]

  // ws layout (16 MB; verified available since r5)
  float* Et   = (float*)d_ws;                  // exp(2*en@w_en)^T [B][U][T_EN]
  float* de_t = Et + (size_t)B_ * U_ * T_EN_;  // exp(2*de@w_de)   [B*T_DE][U]
  short* p    = (short*)(de_t + (size_t)B_ * T_DE_ * U_);
  short* en_hi = p;                 p += 2097152;   // B*T_EN*D
  short* en_lo = p;                 p += 2097152;
  short* de_hi = p;                 p += 524288;    // B*T_DE*D
  short* de_lo = p;                 p += 524288;
  short* wen_hi = p;                p += 131072;    // D*U
  short* wen_lo = p;                p += 131072;
  short* wde_hi = p;                p += 131072;
  short* wde_lo = p;                p += 131072;

  prepack_kernel<<<dim3(1408), 256, 0, stream>>>(
      en, de, w_en, w_de, en_hi, en_lo, de_hi, de_lo,
      wen_hi, wen_lo, wde_hi, wde_lo);
  mfma_proj_kernel<<<dim3(640), 256, 0, stream>>>(
      en_hi, en_lo, de_hi, de_lo, wen_hi, wen_lo, wde_hi, wde_lo, Et, de_t);
  attn_mu_softmax_kernel<<<dim3(256), 512, 0, stream>>>(
      Et, de_t, nu, mask, out);
}